// Round 6
// baseline (9060.329 us; speedup 1.0000x reference)
//
#include <hip/hip_runtime.h>
#include <hip/hip_bf16.h>

typedef __attribute__((ext_vector_type(8))) short short8;
typedef __attribute__((ext_vector_type(4))) float floatx4;
typedef __attribute__((ext_vector_type(4))) unsigned int uintx4;
typedef unsigned int u32;

#define Bb 32
#define Ss 2048
#define Ii 256
#define Hh 256

// ws layout:
//   [8192, 73728)  tagged ring: u32 ring[2][32][256], word = (tag<<16) | bf16(h)
//   [131072, ...)  gx: bf16 pre-activation fragments (round-2 layout, proven)
#define RING_OFF 8192
#define GX_OFF   131072

#define RETRY_DEAD (1u << 22)

__device__ __forceinline__ unsigned short f2bf(float f) {
    unsigned int u = __float_as_uint(f);
    u += 0x7fffu + ((u >> 16) & 1u);   // RNE
    return (unsigned short)(u >> 16);
}
__device__ __forceinline__ float bf2f_lo(u32 w) { return __uint_as_float(w << 16); }
__device__ __forceinline__ float bf2f_hi(u32 w) { return __uint_as_float(w & 0xffff0000u); }

__device__ __forceinline__ float fast_sigmoid(float x) {
    return __builtin_amdgcn_rcpf(1.0f + __expf(-x));
}
__device__ __forceinline__ float fast_tanh(float x) {
    return 1.0f - 2.0f * __builtin_amdgcn_rcpf(__expf(2.0f * x) + 1.0f);
}

// one-shot batched read of all 8 K-chunks (32 tagged u32 / lane) + single wait.
// Loads and waitcnt live in ONE asm block so the compiler cannot hoist register
// uses above the wait (proven pattern from round 5).
__device__ __forceinline__ void ring_load_all(const u32* p, uintx4 A[8], uintx4 B[8]) {
    asm volatile(
        "global_load_dwordx4 %0, %16, off sc0 sc1\n\t"
        "global_load_dwordx4 %1, %16, off offset:16 sc0 sc1\n\t"
        "global_load_dwordx4 %2, %16, off offset:128 sc0 sc1\n\t"
        "global_load_dwordx4 %3, %16, off offset:144 sc0 sc1\n\t"
        "global_load_dwordx4 %4, %16, off offset:256 sc0 sc1\n\t"
        "global_load_dwordx4 %5, %16, off offset:272 sc0 sc1\n\t"
        "global_load_dwordx4 %6, %16, off offset:384 sc0 sc1\n\t"
        "global_load_dwordx4 %7, %16, off offset:400 sc0 sc1\n\t"
        "global_load_dwordx4 %8, %16, off offset:512 sc0 sc1\n\t"
        "global_load_dwordx4 %9, %16, off offset:528 sc0 sc1\n\t"
        "global_load_dwordx4 %10, %16, off offset:640 sc0 sc1\n\t"
        "global_load_dwordx4 %11, %16, off offset:656 sc0 sc1\n\t"
        "global_load_dwordx4 %12, %16, off offset:768 sc0 sc1\n\t"
        "global_load_dwordx4 %13, %16, off offset:784 sc0 sc1\n\t"
        "global_load_dwordx4 %14, %16, off offset:896 sc0 sc1\n\t"
        "global_load_dwordx4 %15, %16, off offset:912 sc0 sc1\n\t"
        "s_waitcnt vmcnt(0)"
        : "=v"(A[0]), "=v"(B[0]), "=v"(A[1]), "=v"(B[1]),
          "=v"(A[2]), "=v"(B[2]), "=v"(A[3]), "=v"(B[3]),
          "=v"(A[4]), "=v"(B[4]), "=v"(A[5]), "=v"(B[5]),
          "=v"(A[6]), "=v"(B[6]), "=v"(A[7]), "=v"(B[7])
        : "v"(p) : "memory");
}

// ---------------- Phase 1: gx[t] = x_t @ Wx_all + b_all (byte-identical to round 2, proven)
__global__ __launch_bounds__(256, 2)
void lstm_gx_kernel(const float* __restrict__ x,
                    const float* __restrict__ Wf, const float* __restrict__ bfp,
                    const float* __restrict__ Wi, const float* __restrict__ bip,
                    const float* __restrict__ Wc, const float* __restrict__ bcp,
                    const float* __restrict__ Wo, const float* __restrict__ bop,
                    u32* __restrict__ gx)
{
    const int tid = threadIdx.x, wave = tid >> 6, lane = tid & 63;
    const int ln = lane & 15, lg = lane >> 4;
    const int combo = blockIdx.x & 7;
    const int tbase = (blockIdx.x >> 3) * 8;
    const int wg = ((combo & 1) << 2) + wave;
    const int chalf = (combo >> 1) & 1, mtile = combo >> 2;
    const int j0 = wg * 32 + chalf * 16, r0 = mtile * 16;
    const int wv = wg * 4 + chalf * 2 + mtile;

    const float* Wg[4] = {Wf, Wi, Wc, Wo};
    const float* bg[4] = {bfp, bip, bcp, bop};
    float bias[4];
#pragma unroll
    for (int g = 0; g < 4; ++g) bias[g] = bg[g][j0 + ln];

    short8 Bf[4][8];
#pragma unroll
    for (int g = 0; g < 4; ++g)
#pragma unroll
        for (int ks = 0; ks < 8; ++ks) {
            short8 v;
#pragma unroll
            for (int i = 0; i < 8; ++i) {
                int k = 256 + 32 * ks + 8 * lg + i;
                v[i] = (short)f2bf(Wg[g][k * Hh + (j0 + ln)]);
            }
            Bf[g][ks] = v;
        }

    for (int it = 0; it < 8; ++it) {
        int t = tbase + it;
        short8 xf[8];
#pragma unroll
        for (int ks = 0; ks < 8; ++ks) {
            const float* px = x + (r0 + ln) * (Ss * Ii) + t * Ii + 32 * ks + 8 * lg;
            floatx4 a = *(const floatx4*)px;
            floatx4 b = *(const floatx4*)(px + 4);
            short8 v;
#pragma unroll
            for (int q = 0; q < 4; ++q) { v[q] = (short)f2bf(a[q]); v[4 + q] = (short)f2bf(b[q]); }
            xf[ks] = v;
        }
        floatx4 acc[4];
#pragma unroll
        for (int g = 0; g < 4; ++g) acc[g] = (floatx4){0.f, 0.f, 0.f, 0.f};
#pragma unroll
        for (int ks = 0; ks < 8; ++ks)
#pragma unroll
            for (int g = 0; g < 4; ++g)
                acc[g] = __builtin_amdgcn_mfma_f32_16x16x32_bf16(xf[ks], Bf[g][ks], acc[g], 0, 0, 0);

        u32 o[8];
#pragma unroll
        for (int g = 0; g < 4; ++g)
#pragma unroll
            for (int rp = 0; rp < 2; ++rp) {
                float v0 = acc[g][2 * rp] + bias[g];
                float v1 = acc[g][2 * rp + 1] + bias[g];
                o[g * 2 + rp] = (u32)f2bf(v0) | ((u32)f2bf(v1) << 16);
            }
        u32* dst = gx + ((size_t)(t * 32 + wv) * 64 + lane) * 8;
        ((uintx4*)dst)[0] = (uintx4){o[0], o[1], o[2], o[3]};
        ((uintx4*)dst)[1] = (uintx4){o[4], o[5], o[6], o[7]};
    }
}

// ---------------- Phase 2: 8 wgs; self-validating tagged ring; one RTT per step
__global__ __launch_bounds__(256, 1)
void lstm_rec6(const float* __restrict__ h0,
               const float* __restrict__ c0,
               const float* __restrict__ Wf,
               const float* __restrict__ Wi,
               const float* __restrict__ Wc,
               const float* __restrict__ Wo,
               float* __restrict__ out,
               u32* ring, const u32* __restrict__ gx)
{
    const int wg = blockIdx.x;
    const int tid = threadIdx.x;
    const int wave = tid >> 6, lane = tid & 63;
    const int mt = wave & 1, chalf = wave >> 1;   // batch-half, col-block
    const int ln = lane & 15, lg = lane >> 4;
    const int j = wg * 32 + chalf * 16 + ln;
    const int wv = wg * 4 + chalf * 2 + mt;       // gx fragment slot (matches writer)

    const float* Wg[4] = {Wf, Wi, Wc, Wo};
    short8 Bfrag[4][8];                            // h-part weights, full K=256
#pragma unroll
    for (int g = 0; g < 4; ++g)
#pragma unroll
        for (int ks = 0; ks < 8; ++ks) {
            short8 v;
#pragma unroll
            for (int i = 0; i < 8; ++i) {
                int k = 32 * ks + 8 * lg + i;
                v[i] = (short)f2bf(Wg[g][k * Hh + j]);
            }
            Bfrag[g][ks] = v;
        }

    float cst[4], hl[4];
#pragma unroll
    for (int r = 0; r < 4; ++r) {
        cst[r] = c0[(16 * mt + 4 * lg + r) * Hh + j];
        hl[r] = 0.0f;
    }

    // ---- publish h0 tile (tag 1) into slot 0: fire-and-forget relaxed stores
    {
        u32* pw = ring + (16 * mt + 4 * lg) * 256 + j;
#pragma unroll
        for (int r = 0; r < 4; ++r)
            __hip_atomic_store(pw + 256 * r,
                               (1u << 16) | (u32)f2bf(h0[(16 * mt + 4 * lg + r) * Hh + j]),
                               __ATOMIC_RELAXED, __HIP_MEMORY_SCOPE_AGENT);
    }

    uintx4 g0, g1;
    {
        const uintx4* p = (const uintx4*)(gx + ((size_t)wv * 64 + lane) * 8);
        g0 = p[0]; g1 = p[1];
    }

    const int myrowbase = (16 * mt + ln) * 256 + 8 * lg;   // u32 index within slot

    for (int t = 0; t < Ss; ++t) {
        const u32 want = (u32)(t + 1) << 16;
        const u32* pd = ring + ((t & 1) ? 8192 : 0) + myrowbase;

        // ---- acc init from gx + prefetch next step's gx (independent of the poll)
        floatx4 acc[4];
        acc[0] = (floatx4){bf2f_lo(g0.x), bf2f_hi(g0.x), bf2f_lo(g0.y), bf2f_hi(g0.y)};
        acc[1] = (floatx4){bf2f_lo(g0.z), bf2f_hi(g0.z), bf2f_lo(g0.w), bf2f_hi(g0.w)};
        acc[2] = (floatx4){bf2f_lo(g1.x), bf2f_hi(g1.x), bf2f_lo(g1.y), bf2f_hi(g1.y)};
        acc[3] = (floatx4){bf2f_lo(g1.z), bf2f_hi(g1.z), bf2f_lo(g1.w), bf2f_hi(g1.w)};
        if (t + 1 < Ss) {
            const uintx4* pn = (const uintx4*)(gx + ((size_t)((t + 1) * 32 + wv) * 64 + lane) * 8);
            g0 = pn[0]; g1 = pn[1];
        }

        // ---- poll: data IS the sentinel. Chunk ks (producer wg ks) validates
        // independently; valid chunks MFMA immediately and leave the poll set.
        u32 pend = 0xFFu, it = 0;
        do {
            uintx4 A[8], B[8];
            ring_load_all(pd, A, B);
#pragma unroll
            for (int ks = 0; ks < 8; ++ks) {
                if (pend & (1u << ks)) {
                    u32 bad = ((A[ks].x ^ want) | (A[ks].y ^ want) |
                               (A[ks].z ^ want) | (A[ks].w ^ want) |
                               (B[ks].x ^ want) | (B[ks].y ^ want) |
                               (B[ks].z ^ want) | (B[ks].w ^ want)) & 0xFFFF0000u;
                    if (!__any((int)(bad != 0))) {
                        union { u32 u[4]; short8 s; } f;
                        f.u[0] = __builtin_amdgcn_perm(A[ks].y, A[ks].x, 0x05040100u);
                        f.u[1] = __builtin_amdgcn_perm(A[ks].w, A[ks].z, 0x05040100u);
                        f.u[2] = __builtin_amdgcn_perm(B[ks].y, B[ks].x, 0x05040100u);
                        f.u[3] = __builtin_amdgcn_perm(B[ks].w, B[ks].z, 0x05040100u);
#pragma unroll
                        for (int g = 0; g < 4; ++g)
                            acc[g] = __builtin_amdgcn_mfma_f32_16x16x32_bf16(f.s, Bfrag[g][ks], acc[g], 0, 0, 0);
                        pend &= ~(1u << ks);
                    }
                }
            }
            if (++it >= RETRY_DEAD) break;   // terminate, never hang
        } while (pend);

        // ---- gates + state update
        float hnew[4];
#pragma unroll
        for (int r = 0; r < 4; ++r) {
            float fg = fast_sigmoid(acc[0][r]);
            float ig = fast_sigmoid(acc[1][r]);
            float cd = fast_tanh(acc[2][r]);
            float og = fast_sigmoid(acc[3][r]);
            float c  = cst[r] * fg + ig * cd;
            cst[r] = c;
            hnew[r] = og * fast_tanh(c);
            hl[r] = hnew[r];
        }

        // ---- publish h_{t+1} (tag t+2): fire-and-forget, no drain, then HBM out
        {
            const u32 ntag = (u32)(t + 2) << 16;
            u32* pw = ring + (((t + 1) & 1) ? 8192 : 0) + (16 * mt + 4 * lg) * 256 + j;
#pragma unroll
            for (int r = 0; r < 4; ++r)
                __hip_atomic_store(pw + 256 * r, ntag | (u32)f2bf(hnew[r]),
                                   __ATOMIC_RELAXED, __HIP_MEMORY_SCOPE_AGENT);
        }
#pragma unroll
        for (int r = 0; r < 4; ++r)
            out[(16 * mt + 4 * lg + r) * (Ss * Hh) + t * Hh + j] = hnew[r];
    }

    float* hfo = out + Bb * Ss * Hh;
    float* cfo = hfo + Bb * Hh;
#pragma unroll
    for (int r = 0; r < 4; ++r) {
        int b = 16 * mt + 4 * lg + r;
        hfo[b * Hh + j] = hl[r];
        cfo[b * Hh + j] = cst[r];
    }
}

extern "C" void kernel_launch(void* const* d_in, const int* in_sizes, int n_in,
                              void* d_out, int out_size, void* d_ws, size_t ws_size,
                              hipStream_t stream) {
    (void)in_sizes; (void)n_in; (void)out_size; (void)ws_size;
    const float* x  = (const float*)d_in[0];
    const float* h0 = (const float*)d_in[1];
    const float* c0 = (const float*)d_in[2];
    const float* Wf = (const float*)d_in[3]; const float* bf = (const float*)d_in[4];
    const float* Wi = (const float*)d_in[5]; const float* bi = (const float*)d_in[6];
    const float* Wc = (const float*)d_in[7]; const float* bc = (const float*)d_in[8];
    const float* Wo = (const float*)d_in[9]; const float* bo = (const float*)d_in[10];

    u32* ring = (u32*)((char*)d_ws + RING_OFF);
    u32* gx   = (u32*)((char*)d_ws + GX_OFF);

    // No ws zero-init needed: tagged protocol is poison-safe (0xAAAA tag never matches)

    hipLaunchKernelGGL(lstm_gx_kernel, dim3(2048), dim3(256), 0, stream,
                       x, Wf, bf, Wi, bi, Wc, bc, Wo, bo, gx);
    hipLaunchKernelGGL(lstm_rec6, dim3(8), dim3(256), 0, stream,
                       h0, c0, Wf, Wi, Wc, Wo, (float*)d_out, ring, gx);
}